// Round 17
// baseline (222.430 us; speedup 1.0000x reference)
//
#include <hip/hip_runtime.h>
#include <hip/hip_bf16.h>
#include <hip/hip_cooperative_groups.h>

namespace cg = cooperative_groups;

typedef float f32x4 __attribute__((ext_vector_type(4)));
typedef long  lx2   __attribute__((ext_vector_type(2)));

#define B_ROWS 4096
#define NROWS  8192
#define DDIM   512
#define NTILE  2080
// exp(sim/T) = exp2(sim * (1/T)/ln2), T=0.5 -> 2/ln2
#define SCALE2 2.8853900817779268f

// zq tiled fp8 layout: 1 KB segment per (row-group R = row>>4, k-group G = k>>6).
// seg base = (R*8+G)*1024. Lane l = quad*16+l16 owns 16 B at l*16:
//   bytes 0..7 = fragment for k-tile 2G, bytes 8..15 = fragment for k-tile 2G+1.
// scratch: 64x64 grid of 128-float cells, each written EXACTLY once.

// ================= fused cooperative kernel: normalize -> simexp -> finalize ======
__global__ __launch_bounds__(256) void fused_kernel(
    const float* __restrict__ h1, const float* __restrict__ h2,
    unsigned char* __restrict__ zq, float* __restrict__ scratch,
    float* __restrict__ pos, float* __restrict__ out) {
  __shared__ __align__(16) unsigned char As[16384];  // phase1: tile; phase2: A segs
  __shared__ __align__(16) unsigned char Bs[16384];
  __shared__ float rp[256];
  __shared__ float cp[256];

  cg::grid_group grid = cg::this_grid();
  const int bid  = blockIdx.x;
  const int tid  = threadIdx.x;
  const int wave = tid >> 6;
  const int lane = tid & 63;

  if (bid == 0 && tid == 0) out[0] = 0.0f;

  // ---------------- phase 1: normalize (grid-stride over 512 row-groups) ----------
  {
    const int G = lane >> 3, g8 = lane & 7;
    const int quad = g8 & 3, half = g8 >> 2;
    for (int rg = bid; rg < NROWS / 16; rg += gridDim.x) {
      #pragma unroll
      for (int it = 0; it < 4; ++it) {
        const int r = it * 4 + wave;
        const int row = rg * 16 + r;
        const float* src = (row < B_ROWS) ? (h1 + (size_t)row * DDIM)
                                          : (h2 + (size_t)(row - B_ROWS) * DDIM);
        float4 v0 = *(const float4*)(src + lane * 8);
        float4 v1 = *(const float4*)(src + lane * 8 + 4);
        float ss = v0.x*v0.x + v0.y*v0.y + v0.z*v0.z + v0.w*v0.w
                 + v1.x*v1.x + v1.y*v1.y + v1.z*v1.z + v1.w*v1.w;
        #pragma unroll
        for (int m = 1; m <= 32; m <<= 1) ss += __shfl_xor(ss, m);
        float sc = 1.0f / fmaxf(sqrtf(ss), 1e-8f);
        int lo = 0, hi = 0;
        lo = __builtin_amdgcn_cvt_pk_fp8_f32(v0.x*sc, v0.y*sc, lo, 0);
        lo = __builtin_amdgcn_cvt_pk_fp8_f32(v0.z*sc, v0.w*sc, lo, 1);
        hi = __builtin_amdgcn_cvt_pk_fp8_f32(v1.x*sc, v1.y*sc, hi, 0);
        hi = __builtin_amdgcn_cvt_pk_fp8_f32(v1.z*sc, v1.w*sc, hi, 1);
        *(int2*)(As + G * 1024 + (quad * 16 + r) * 16 + half * 8) = make_int2(lo, hi);
      }
      __syncthreads();
      int4 w0 = *(const int4*)(As + tid * 16);
      int4 w1 = *(const int4*)(As + 4096 + tid * 16);
      *(int4*)(zq + (size_t)rg * 8192 + tid * 16) = w0;
      *(int4*)(zq + (size_t)rg * 8192 + 4096 + tid * 16) = w1;
      __syncthreads();   // tile reuse safe for next band
    }
  }
  grid.sync();

  // ---------------- phase 2: simexp (grid-stride over 2080 triangle tiles) --------
  {
    const int wm = wave >> 1, wn = wave & 1;
    const int quad = lane >> 4;
    const int l16  = lane & 15;

    for (int t = bid; t < NTILE; t += gridDim.x) {
      int bi = (int)((sqrtf(8.0f * (float)t + 1.0f) - 1.0f) * 0.5f);
      while ((bi + 1) * (bi + 2) / 2 <= t) ++bi;
      while (bi * (bi + 1) / 2 > t) --bi;
      int bj = t - bi * (bi + 1) / 2;
      const int rowBlk = bi * 128;
      const int colBlk = bj * 128;
      const bool isDiag = (bi == bj);

      const unsigned char* aBase = zq + (size_t)bi * 65536;  // 8 rg x 8 G x 1 KB
      const unsigned char* bBase = zq + (size_t)bj * 65536;

      f32x4 acc[4][4] = {};

      #pragma unroll
      for (int h = 0; h < 4; ++h) {            // K-quarter: G = h*2, h*2+1
        if (h) __syncthreads();
        #pragma unroll
        for (int i = 0; i < 4; ++i) {
          const int s = wave * 4 + i;          // seg 0..15
          const int rg = s >> 1, gl = s & 1;
          const size_t goff = (size_t)(rg * 8 + h * 2 + gl) * 1024 + lane * 16;
          __builtin_amdgcn_global_load_lds(
              (const __attribute__((address_space(1))) unsigned int*)(aBase + goff),
              (__attribute__((address_space(3))) unsigned int*)(As + s * 1024), 16, 0, 0);
          __builtin_amdgcn_global_load_lds(
              (const __attribute__((address_space(1))) unsigned int*)(bBase + goff),
              (__attribute__((address_space(3))) unsigned int*)(Bs + s * 1024), 16, 0, 0);
        }
        __syncthreads();                       // staged data visible

        #pragma unroll
        for (int gl = 0; gl < 2; ++gl) {
          lx2 afr[4], bfr[4];
          #pragma unroll
          for (int rt = 0; rt < 4; ++rt)
            afr[rt] = *(const lx2*)(As + (size_t)((wm * 4 + rt) * 2 + gl) * 1024 + lane * 16);
          #pragma unroll
          for (int ct = 0; ct < 4; ++ct)
            bfr[ct] = *(const lx2*)(Bs + (size_t)((wn * 4 + ct) * 2 + gl) * 1024 + lane * 16);
          #pragma unroll
          for (int rt = 0; rt < 4; ++rt)
            #pragma unroll
            for (int ct = 0; ct < 4; ++ct) {
              acc[rt][ct] = __builtin_amdgcn_mfma_f32_16x16x32_fp8_fp8(
                  afr[rt].x, bfr[ct].x, acc[rt][ct], 0, 0, 0);
              acc[rt][ct] = __builtin_amdgcn_mfma_f32_16x16x32_fp8_fp8(
                  afr[rt].y, bfr[ct].y, acc[rt][ct], 0, 0, 0);
            }
        }
      }

      // epilogue v3 (R14): unique-slot plain LDS writes, ONE barrier, plain stores
      const bool posBlk = (bi - bj == 32);
      float colpart[4] = {0.f, 0.f, 0.f, 0.f};
      #pragma unroll
      for (int rt = 0; rt < 4; ++rt) {
        #pragma unroll
        for (int r = 0; r < 4; ++r) {
          const int lrow = wm * 64 + rt * 16 + quad * 4 + r;
          const int grow = rowBlk + lrow;
          float s = 0.f;
          #pragma unroll
          for (int ct = 0; ct < 4; ++ct) {
            const int gcol = colBlk + wn * 64 + ct * 16 + l16;
            float sv = acc[rt][ct][r];
            float e = exp2f(sv * SCALE2);
            if (isDiag && grow == gcol) e = 0.f;
            if (posBlk && grow - B_ROWS == gcol) pos[gcol] = sv;
            s += e;
            colpart[ct] += e;
          }
          s += __shfl_xor(s, 1);
          s += __shfl_xor(s, 2);
          s += __shfl_xor(s, 4);
          s += __shfl_xor(s, 8);
          if (l16 == 0) rp[lrow * 2 + wn] = s;
        }
      }
      #pragma unroll
      for (int ct = 0; ct < 4; ++ct) {
        float c = colpart[ct];
        c += __shfl_xor(c, 16);
        c += __shfl_xor(c, 32);
        if (quad == 0) cp[(wn * 64 + ct * 16 + l16) * 2 + wm] = c;
      }
      __syncthreads();
      if (tid < 128) {
        scratch[(size_t)(bi * 64 + bj) * 128 + tid] = rp[tid * 2] + rp[tid * 2 + 1];
      } else if (!isDiag) {
        const int c = tid - 128;
        scratch[(size_t)(bj * 64 + bi) * 128 + c] = cp[c * 2] + cp[c * 2 + 1];
      }
    }
  }
  grid.sync();

  // ---------------- phase 3: finalize (grid-stride over 8192 rows) ----------------
  {
    float accl = 0.f;
    for (int gid = bid * 256 + tid; gid < NROWS; gid += gridDim.x * 256) {
      const int band = gid >> 7, r = gid & 127;
      const float* base = scratch + (size_t)band * 64 * 128 + r;
      float s = 0.f;
      #pragma unroll 8
      for (int c = 0; c < 64; ++c) s += base[c * 128];
      accl += __logf(s) - 2.0f * pos[gid & (B_ROWS - 1)];
    }
    #pragma unroll
    for (int m = 1; m <= 32; m <<= 1) accl += __shfl_xor(accl, m);
    if (lane == 0) rp[wave] = accl;
    __syncthreads();
    if (tid == 0) {
      float s = rp[0] + rp[1] + rp[2] + rp[3];
      if (s != 0.0f) atomicAdd(out, s * (1.0f / NROWS));
    }
  }
}

// ================= fallback path (R14 three-kernel, used if no cooperative) =======
__global__ __launch_bounds__(256) void normalize_kernel(
    const float* __restrict__ h1, const float* __restrict__ h2,
    unsigned char* __restrict__ zq, float* __restrict__ out) {
  __shared__ __align__(16) unsigned char tile[8192];
  if (blockIdx.x == 0 && threadIdx.x == 0) out[0] = 0.0f;
  const int wave = threadIdx.x >> 6;
  const int lane = threadIdx.x & 63;
  const int rg = blockIdx.x;
  const int G = lane >> 3, g8 = lane & 7;
  const int quad = g8 & 3, half = g8 >> 2;
  #pragma unroll
  for (int it = 0; it < 4; ++it) {
    const int r = it * 4 + wave;
    const int row = rg * 16 + r;
    const float* src = (row < B_ROWS) ? (h1 + (size_t)row * DDIM)
                                      : (h2 + (size_t)(row - B_ROWS) * DDIM);
    float4 v0 = *(const float4*)(src + lane * 8);
    float4 v1 = *(const float4*)(src + lane * 8 + 4);
    float ss = v0.x*v0.x + v0.y*v0.y + v0.z*v0.z + v0.w*v0.w
             + v1.x*v1.x + v1.y*v1.y + v1.z*v1.z + v1.w*v1.w;
    #pragma unroll
    for (int m = 1; m <= 32; m <<= 1) ss += __shfl_xor(ss, m);
    float sc = 1.0f / fmaxf(sqrtf(ss), 1e-8f);
    int lo = 0, hi = 0;
    lo = __builtin_amdgcn_cvt_pk_fp8_f32(v0.x*sc, v0.y*sc, lo, 0);
    lo = __builtin_amdgcn_cvt_pk_fp8_f32(v0.z*sc, v0.w*sc, lo, 1);
    hi = __builtin_amdgcn_cvt_pk_fp8_f32(v1.x*sc, v1.y*sc, hi, 0);
    hi = __builtin_amdgcn_cvt_pk_fp8_f32(v1.z*sc, v1.w*sc, hi, 1);
    *(int2*)(tile + G * 1024 + (quad * 16 + r) * 16 + half * 8) = make_int2(lo, hi);
  }
  __syncthreads();
  int4 w0 = *(const int4*)(tile + threadIdx.x * 16);
  int4 w1 = *(const int4*)(tile + 4096 + threadIdx.x * 16);
  *(int4*)(zq + (size_t)rg * 8192 + threadIdx.x * 16) = w0;
  *(int4*)(zq + (size_t)rg * 8192 + 4096 + threadIdx.x * 16) = w1;
}

__global__ __launch_bounds__(256) void simexp_kernel(
    const unsigned char* __restrict__ zq, float* __restrict__ scratch,
    float* __restrict__ pos) {
  __shared__ __align__(16) unsigned char As[16384];
  __shared__ __align__(16) unsigned char Bs[16384];
  __shared__ float rp[256];
  __shared__ float cp[256];
  const int tid  = threadIdx.x;
  const int wave = tid >> 6;
  const int lane = tid & 63;
  const int wm = wave >> 1, wn = wave & 1;
  const int quad = lane >> 4;
  const int l16  = lane & 15;
  int t  = blockIdx.x;
  int bi = (int)((sqrtf(8.0f * (float)t + 1.0f) - 1.0f) * 0.5f);
  while ((bi + 1) * (bi + 2) / 2 <= t) ++bi;
  while (bi * (bi + 1) / 2 > t) --bi;
  int bj = t - bi * (bi + 1) / 2;
  const int rowBlk = bi * 128;
  const int colBlk = bj * 128;
  const bool isDiag = (bi == bj);
  const unsigned char* aBase = zq + (size_t)bi * 65536;
  const unsigned char* bBase = zq + (size_t)bj * 65536;
  f32x4 acc[4][4] = {};
  #pragma unroll
  for (int h = 0; h < 4; ++h) {
    if (h) __syncthreads();
    #pragma unroll
    for (int i = 0; i < 4; ++i) {
      const int s = wave * 4 + i;
      const int rg = s >> 1, gl = s & 1;
      const size_t goff = (size_t)(rg * 8 + h * 2 + gl) * 1024 + lane * 16;
      __builtin_amdgcn_global_load_lds(
          (const __attribute__((address_space(1))) unsigned int*)(aBase + goff),
          (__attribute__((address_space(3))) unsigned int*)(As + s * 1024), 16, 0, 0);
      __builtin_amdgcn_global_load_lds(
          (const __attribute__((address_space(1))) unsigned int*)(bBase + goff),
          (__attribute__((address_space(3))) unsigned int*)(Bs + s * 1024), 16, 0, 0);
    }
    __syncthreads();
    #pragma unroll
    for (int gl = 0; gl < 2; ++gl) {
      lx2 afr[4], bfr[4];
      #pragma unroll
      for (int rt = 0; rt < 4; ++rt)
        afr[rt] = *(const lx2*)(As + (size_t)((wm * 4 + rt) * 2 + gl) * 1024 + lane * 16);
      #pragma unroll
      for (int ct = 0; ct < 4; ++ct)
        bfr[ct] = *(const lx2*)(Bs + (size_t)((wn * 4 + ct) * 2 + gl) * 1024 + lane * 16);
      #pragma unroll
      for (int rt = 0; rt < 4; ++rt)
        #pragma unroll
        for (int ct = 0; ct < 4; ++ct) {
          acc[rt][ct] = __builtin_amdgcn_mfma_f32_16x16x32_fp8_fp8(
              afr[rt].x, bfr[ct].x, acc[rt][ct], 0, 0, 0);
          acc[rt][ct] = __builtin_amdgcn_mfma_f32_16x16x32_fp8_fp8(
              afr[rt].y, bfr[ct].y, acc[rt][ct], 0, 0, 0);
        }
    }
  }
  const bool posBlk = (bi - bj == 32);
  float colpart[4] = {0.f, 0.f, 0.f, 0.f};
  #pragma unroll
  for (int rt = 0; rt < 4; ++rt) {
    #pragma unroll
    for (int r = 0; r < 4; ++r) {
      const int lrow = wm * 64 + rt * 16 + quad * 4 + r;
      const int grow = rowBlk + lrow;
      float s = 0.f;
      #pragma unroll
      for (int ct = 0; ct < 4; ++ct) {
        const int gcol = colBlk + wn * 64 + ct * 16 + l16;
        float sv = acc[rt][ct][r];
        float e = exp2f(sv * SCALE2);
        if (isDiag && grow == gcol) e = 0.f;
        if (posBlk && grow - B_ROWS == gcol) pos[gcol] = sv;
        s += e;
        colpart[ct] += e;
      }
      s += __shfl_xor(s, 1);
      s += __shfl_xor(s, 2);
      s += __shfl_xor(s, 4);
      s += __shfl_xor(s, 8);
      if (l16 == 0) rp[lrow * 2 + wn] = s;
    }
  }
  #pragma unroll
  for (int ct = 0; ct < 4; ++ct) {
    float c = colpart[ct];
    c += __shfl_xor(c, 16);
    c += __shfl_xor(c, 32);
    if (quad == 0) cp[(wn * 64 + ct * 16 + l16) * 2 + wm] = c;
  }
  __syncthreads();
  if (tid < 128) {
    scratch[(size_t)(bi * 64 + bj) * 128 + tid] = rp[tid * 2] + rp[tid * 2 + 1];
  } else if (!isDiag) {
    const int c = tid - 128;
    scratch[(size_t)(bj * 64 + bi) * 128 + c] = cp[c * 2] + cp[c * 2 + 1];
  }
}

__global__ __launch_bounds__(256) void finalize_kernel(
    const float* __restrict__ scratch, const float* __restrict__ pos,
    float* __restrict__ out) {
  __shared__ float red[4];
  const int gid = blockIdx.x * 256 + threadIdx.x;
  const int band = gid >> 7, r = gid & 127;
  const float* base = scratch + (size_t)band * 64 * 128 + r;
  float s = 0.f;
  #pragma unroll 8
  for (int c = 0; c < 64; ++c) s += base[c * 128];
  float loss = __logf(s) - 2.0f * pos[gid & (B_ROWS - 1)];
  #pragma unroll
  for (int m = 1; m <= 32; m <<= 1) loss += __shfl_xor(loss, m);
  const int wave = threadIdx.x >> 6;
  const int lane = threadIdx.x & 63;
  if (lane == 0) red[wave] = loss;
  __syncthreads();
  if (threadIdx.x == 0)
    atomicAdd(out, (red[0] + red[1] + red[2] + red[3]) * (1.0f / NROWS));
}

extern "C" void kernel_launch(void* const* d_in, const int* in_sizes, int n_in,
                              void* d_out, int out_size, void* d_ws, size_t ws_size,
                              hipStream_t stream) {
  const float* h1 = (const float*)d_in[0];
  const float* h2 = (const float*)d_in[1];
  float* out = (float*)d_out;
  unsigned char* zq = (unsigned char*)d_ws;                        // 4 MiB fp8
  float* scratch = (float*)((char*)d_ws + (size_t)NROWS * DDIM);   // 2 MiB
  float* pos     = scratch + 64 * 64 * 128;                        // 16 KiB

  int dev = 0;
  hipGetDevice(&dev);
  int coop = 0, nCU = 0;
  hipDeviceGetAttribute(&coop, hipDeviceAttributeCooperativeLaunch, dev);
  hipDeviceGetAttribute(&nCU, hipDeviceAttributeMultiprocessorCount, dev);
  int maxBlk = 0;
  hipOccupancyMaxActiveBlocksPerMultiprocessor(&maxBlk, (const void*)fused_kernel,
                                               256, 0);
  if (coop && maxBlk > 0 && nCU > 0) {
    int gridN = maxBlk * nCU;
    if (gridN > NTILE) gridN = NTILE;
    void* args[] = {(void*)&h1, (void*)&h2, (void*)&zq,
                    (void*)&scratch, (void*)&pos, (void*)&out};
    hipLaunchCooperativeKernel((void*)fused_kernel, dim3(gridN), dim3(256),
                               args, 0, stream);
    return;
  }
  // fallback: R14 three-kernel path
  normalize_kernel<<<NROWS / 16, 256, 0, stream>>>(h1, h2, zq, out);
  simexp_kernel<<<NTILE, 256, 0, stream>>>(zq, scratch, pos);
  finalize_kernel<<<NROWS / 256, 256, 0, stream>>>(scratch, pos, out);
}

// Round 18
// 104.530 us; speedup vs baseline: 2.1279x; 2.1279x over previous
//
#include <hip/hip_runtime.h>
#include <hip/hip_bf16.h>

typedef float f32x4 __attribute__((ext_vector_type(4)));
typedef long  lx2   __attribute__((ext_vector_type(2)));

#define B_ROWS 4096
#define NROWS  8192
#define DDIM   512
// exp(sim/T) = exp2(sim * (1/T)/ln2), T=0.5 -> 2/ln2
#define SCALE2 2.8853900817779268f

// zq tiled fp8 layout: 1 KB segment per (row-group R = row>>4, k-group G = k>>6).
// seg base = (R*8+G)*1024. Lane l = quad*16+l16 owns 16 B at l*16.
// scratch: 64x64 grid of 128-float cells, each written EXACTLY once (row-parts of
// block (bi,bj) -> cell (bi,bj); col-parts -> cell (bj,bi)); no init, no atomics.

// ---------------- normalize: fp32 -> fp8 e4m3 tiled, LDS-transposed stores ---------
__global__ __launch_bounds__(256) void normalize_kernel(
    const float* __restrict__ h1, const float* __restrict__ h2,
    unsigned char* __restrict__ zq, float* __restrict__ out) {
  __shared__ __align__(16) unsigned char tile[8192];
  if (blockIdx.x == 0 && threadIdx.x == 0) out[0] = 0.0f;

  const int wave = threadIdx.x >> 6;
  const int lane = threadIdx.x & 63;
  const int rg = blockIdx.x;
  const int G = lane >> 3, g8 = lane & 7;
  const int quad = g8 & 3, half = g8 >> 2;

  #pragma unroll
  for (int it = 0; it < 4; ++it) {
    const int r = it * 4 + wave;
    const int row = rg * 16 + r;
    const float* src = (row < B_ROWS) ? (h1 + (size_t)row * DDIM)
                                      : (h2 + (size_t)(row - B_ROWS) * DDIM);
    float4 v0 = *(const float4*)(src + lane * 8);
    float4 v1 = *(const float4*)(src + lane * 8 + 4);
    float ss = v0.x*v0.x + v0.y*v0.y + v0.z*v0.z + v0.w*v0.w
             + v1.x*v1.x + v1.y*v1.y + v1.z*v1.z + v1.w*v1.w;
    #pragma unroll
    for (int m = 1; m <= 32; m <<= 1) ss += __shfl_xor(ss, m);
    float sc = 1.0f / fmaxf(sqrtf(ss), 1e-8f);
    int lo = 0, hi = 0;
    lo = __builtin_amdgcn_cvt_pk_fp8_f32(v0.x*sc, v0.y*sc, lo, 0);
    lo = __builtin_amdgcn_cvt_pk_fp8_f32(v0.z*sc, v0.w*sc, lo, 1);
    hi = __builtin_amdgcn_cvt_pk_fp8_f32(v1.x*sc, v1.y*sc, hi, 0);
    hi = __builtin_amdgcn_cvt_pk_fp8_f32(v1.z*sc, v1.w*sc, hi, 1);
    *(int2*)(tile + G * 1024 + (quad * 16 + r) * 16 + half * 8) = make_int2(lo, hi);
  }
  __syncthreads();
  int4 w0 = *(const int4*)(tile + threadIdx.x * 16);
  int4 w1 = *(const int4*)(tile + 4096 + threadIdx.x * 16);
  *(int4*)(zq + (size_t)rg * 8192 + threadIdx.x * 16) = w0;
  *(int4*)(zq + (size_t)rg * 8192 + 4096 + threadIdx.x * 16) = w1;
}

// ---------------- fused sim GEMM (fp8) + exp + row-sum, lower-triangle blocks ------
// R14 verbatim with ONE change: __launch_bounds__(256, 4) caps total regs at 128
// (64 arch + 64 acc) -> 4 blocks/CU (vs 3). Blocks/CU is the one proven positive
// lever (R7 2blk=69us -> R9 3blk=58.5us). Spill canary: WRITE_SIZE (2.06 MB now).
__global__ __launch_bounds__(256, 4) void simexp_kernel(
    const unsigned char* __restrict__ zq, float* __restrict__ scratch,
    float* __restrict__ pos) {
  __shared__ __align__(16) unsigned char As[16384];  // 16 segs: s = rg*2+gl
  __shared__ __align__(16) unsigned char Bs[16384];
  __shared__ float rp[256];   // row partials: slot (lrow)*2 + wn
  __shared__ float cp[256];   // col partials: slot (lcol)*2 + wm

  const int tid  = threadIdx.x;
  const int wave = tid >> 6;
  const int lane = tid & 63;
  const int wm = wave >> 1, wn = wave & 1;
  const int quad = lane >> 4;
  const int l16  = lane & 15;

  // unrank triangular block index: t = bi*(bi+1)/2 + bj, bi >= bj
  int t  = blockIdx.x;
  int bi = (int)((sqrtf(8.0f * (float)t + 1.0f) - 1.0f) * 0.5f);
  while ((bi + 1) * (bi + 2) / 2 <= t) ++bi;
  while (bi * (bi + 1) / 2 > t) --bi;
  int bj = t - bi * (bi + 1) / 2;
  const int rowBlk = bi * 128;
  const int colBlk = bj * 128;
  const bool isDiag = (bi == bj);

  const unsigned char* aBase = zq + (size_t)bi * 65536;  // 8 rg x 8 G x 1 KB
  const unsigned char* bBase = zq + (size_t)bj * 65536;

  f32x4 acc[4][4] = {};

  #pragma unroll
  for (int h = 0; h < 4; ++h) {              // K-quarter: G = h*2, h*2+1
    if (h) __syncthreads();                  // waves done reading previous quarter
    #pragma unroll
    for (int i = 0; i < 4; ++i) {
      const int s = wave * 4 + i;            // seg 0..15
      const int rg = s >> 1, gl = s & 1;
      const size_t goff = (size_t)(rg * 8 + h * 2 + gl) * 1024 + lane * 16;
      __builtin_amdgcn_global_load_lds(
          (const __attribute__((address_space(1))) unsigned int*)(aBase + goff),
          (__attribute__((address_space(3))) unsigned int*)(As + s * 1024), 16, 0, 0);
      __builtin_amdgcn_global_load_lds(
          (const __attribute__((address_space(1))) unsigned int*)(bBase + goff),
          (__attribute__((address_space(3))) unsigned int*)(Bs + s * 1024), 16, 0, 0);
    }
    __syncthreads();                         // staged data visible

    #pragma unroll
    for (int gl = 0; gl < 2; ++gl) {
      lx2 afr[4], bfr[4];
      #pragma unroll
      for (int rt = 0; rt < 4; ++rt)
        afr[rt] = *(const lx2*)(As + (size_t)((wm * 4 + rt) * 2 + gl) * 1024 + lane * 16);
      #pragma unroll
      for (int ct = 0; ct < 4; ++ct)
        bfr[ct] = *(const lx2*)(Bs + (size_t)((wn * 4 + ct) * 2 + gl) * 1024 + lane * 16);
      #pragma unroll
      for (int rt = 0; rt < 4; ++rt)
        #pragma unroll
        for (int ct = 0; ct < 4; ++ct) {
          acc[rt][ct] = __builtin_amdgcn_mfma_f32_16x16x32_fp8_fp8(
              afr[rt].x, bfr[ct].x, acc[rt][ct], 0, 0, 0);
          acc[rt][ct] = __builtin_amdgcn_mfma_f32_16x16x32_fp8_fp8(
              afr[rt].y, bfr[ct].y, acc[rt][ct], 0, 0, 0);
        }
    }
  }

  // ---- epilogue v3: exp2 -> unique-slot plain LDS writes -> 1 barrier -> stores ----
  // C/D layout: col = lane&15, row = quad*4 + reg (dtype-independent on gfx950)
  const bool posBlk = (bi - bj == 32);  // contains the +B diagonal
  float colpart[4] = {0.f, 0.f, 0.f, 0.f};
  #pragma unroll
  for (int rt = 0; rt < 4; ++rt) {
    #pragma unroll
    for (int r = 0; r < 4; ++r) {
      const int lrow = wm * 64 + rt * 16 + quad * 4 + r;
      const int grow = rowBlk + lrow;
      float s = 0.f;
      #pragma unroll
      for (int ct = 0; ct < 4; ++ct) {
        const int gcol = colBlk + wn * 64 + ct * 16 + l16;
        float sv = acc[rt][ct][r];
        float e = exp2f(sv * SCALE2);
        if (isDiag && grow == gcol) e = 0.f;
        if (posBlk && grow - B_ROWS == gcol) pos[gcol] = sv;
        s += e;
        colpart[ct] += e;
      }
      s += __shfl_xor(s, 1);
      s += __shfl_xor(s, 2);
      s += __shfl_xor(s, 4);
      s += __shfl_xor(s, 8);
      if (l16 == 0) rp[lrow * 2 + wn] = s;          // single writer per slot
    }
  }
  #pragma unroll
  for (int ct = 0; ct < 4; ++ct) {
    float c = colpart[ct];
    c += __shfl_xor(c, 16);
    c += __shfl_xor(c, 32);
    if (quad == 0) cp[(wn * 64 + ct * 16 + l16) * 2 + wm] = c;  // single writer
  }
  __syncthreads();
  if (tid < 128) {
    scratch[(size_t)(bi * 64 + bj) * 128 + tid] = rp[tid * 2] + rp[tid * 2 + 1];
  } else if (!isDiag) {
    const int c = tid - 128;
    scratch[(size_t)(bj * 64 + bi) * 128 + c] = cp[c * 2] + cp[c * 2 + 1];
  }
}

// ---------------- finalize: rowsum from scratch; loss mean ------------------------
__global__ __launch_bounds__(256) void finalize_kernel(
    const float* __restrict__ scratch, const float* __restrict__ pos,
    float* __restrict__ out) {
  __shared__ float red[4];
  const int gid = blockIdx.x * 256 + threadIdx.x;
  const int band = gid >> 7, r = gid & 127;
  const float* base = scratch + (size_t)band * 64 * 128 + r;
  float s = 0.f;
  #pragma unroll 8
  for (int c = 0; c < 64; ++c) s += base[c * 128];
  float loss = __logf(s) - 2.0f * pos[gid & (B_ROWS - 1)];
  #pragma unroll
  for (int m = 1; m <= 32; m <<= 1) loss += __shfl_xor(loss, m);
  const int wave = threadIdx.x >> 6;
  const int lane = threadIdx.x & 63;
  if (lane == 0) red[wave] = loss;
  __syncthreads();
  if (threadIdx.x == 0)
    atomicAdd(out, (red[0] + red[1] + red[2] + red[3]) * (1.0f / NROWS));
}

extern "C" void kernel_launch(void* const* d_in, const int* in_sizes, int n_in,
                              void* d_out, int out_size, void* d_ws, size_t ws_size,
                              hipStream_t stream) {
  const float* h1 = (const float*)d_in[0];
  const float* h2 = (const float*)d_in[1];
  float* out = (float*)d_out;
  unsigned char* zq = (unsigned char*)d_ws;                        // 4 MiB fp8
  float* scratch = (float*)((char*)d_ws + (size_t)NROWS * DDIM);   // 2 MiB
  float* pos     = scratch + 64 * 64 * 128;                        // 16 KiB

  normalize_kernel<<<NROWS / 16, 256, 0, stream>>>(h1, h2, zq, out);
  simexp_kernel<<<64 * 65 / 2, 256, 0, stream>>>(zq, scratch, pos);
  finalize_kernel<<<NROWS / 256, 256, 0, stream>>>(scratch, pos, out);
}